// Round 5
// baseline (31.688 us; speedup 1.0000x reference)
//
#include <hip/hip_runtime.h>
#include <math.h>
#include <stdint.h>

#define BATCH 32
#define ND 512
#define NC 100
#define JB 8
#define NJT 13          // j0 = 0,8,...,88, last tile j0=92 (overlap; max is idempotent)
#define HALF 256        // n per block (split 2)
#define NT 512
#define BIGNEG 1000000.0f
#define PROW 12         // floats per i-row in partial block (16B-aligned rows)
#define PBLK 1552       // 128*PROW + 8 (R) + 8 pad, 16B-aligned

typedef float f32x8 __attribute__((ext_vector_type(8)));

__global__ __launch_bounds__(NT, 8) void adv_part(
    const float* __restrict__ z, const float* __restrict__ wu,
    const float* __restrict__ wl, float* __restrict__ ws)
{
  // 832 blocks; XCD-chunk swizzle (832 = 8*104, bijective): each XCD gets 4 whole batches
  int id = (blockIdx.x & 7) * (NJT * BATCH * 2 / 8) + (blockIdx.x >> 3);
  const int s  = id & 1;                 // n-half
  const int bj = id >> 1;
  const int b  = bj / NJT;
  const int jt = bj - b * NJT;
  const int j0 = (jt < NJT - 1) ? jt * JB : (NC - JB);

  const int tid  = threadIdx.x;
  const int g    = tid >> 7;             // n-group of 64 within the half
  const int lane = tid & 127;            // i index
  const int iL   = (lane < NC) ? lane : NC - 1;

  __shared__ __align__(16) float s_cr[HALF][2];
  __shared__ float s_red[3][128][9];     // 8 acc + accc, stride 9 (coprime 32)
  __shared__ float s_lin[4][JB];
  __shared__ float s_max_un[1];          // unused pad

  // ---- staging: threads 0..255 own n_local = tid ----
  const float* zb = z + b * (2 * ND);
  float p[JB];
  if (tid < HALF) {
    int n = s * HALF + tid;
    float lo = zb[n], hi = zb[ND + n];
    float cme = 0.5f * (lo + hi);
    float rad = 0.5f * (hi - lo);
    s_cr[tid][0] = cme;
    s_cr[tid][1] = rad;
    const float* wlr = wl + ((size_t)b * ND + n) * NC + j0;   // 16B-aligned (j0%4==0)
    float4 wa = *(const float4*)wlr;
    float4 wb = *(const float4*)(wlr + 4);
    p[0] = cme * wa.x; p[1] = cme * wa.y; p[2] = cme * wa.z; p[3] = cme * wa.w;
    p[4] = cme * wb.x; p[5] = cme * wb.y; p[6] = cme * wb.z; p[7] = cme * wb.w;
  } else {
#pragma unroll
    for (int jj = 0; jj < JB; ++jj) p[jj] = 0.0f;
  }
#pragma unroll
  for (int off = 32; off; off >>= 1) {
#pragma unroll
    for (int jj = 0; jj < JB; ++jj) p[jj] += __shfl_down(p[jj], off, 64);
  }
  if ((tid & 63) == 0 && tid < HALF) {
#pragma unroll
    for (int jj = 0; jj < JB; ++jj) s_lin[tid >> 6][jj] = p[jj];
  }
  __syncthreads();

  // ---- main loop: 16 chunks x 4 n ----
  float acc[JB] = {0, 0, 0, 0, 0, 0, 0, 0};
  float accc = 0.f;
  const int n0 = s * HALF + g * 64;
  const float* wup = wu + ((size_t)b * ND + n0) * NC + iL;
  const float* crp = &s_cr[g * 64][0];

  uint64_t va = (uint64_t)(wl + ((size_t)b * ND + n0) * NC + j0);
  uint32_t lo32 = __builtin_amdgcn_readfirstlane((uint32_t)(va & 0xffffffffu));
  uint32_t hi32 = __builtin_amdgcn_readfirstlane((uint32_t)(va >> 32));
  uint64_t sa = ((uint64_t)hi32 << 32) | (uint64_t)lo32;

  for (int ch = 0; ch < 16; ++ch) {
    float w0 = wup[0], w1 = wup[NC], w2 = wup[2 * NC], w3 = wup[3 * NC];
    f32x8 q0, q1, q2, q3;
    asm volatile(
        "s_load_dwordx8 %0, %4, 0x0\n\t"
        "s_load_dwordx8 %1, %4, 0x190\n\t"
        "s_load_dwordx8 %2, %4, 0x320\n\t"
        "s_load_dwordx8 %3, %4, 0x4b0\n\t"
        "s_waitcnt lgkmcnt(0)"
        : "=&s"(q0), "=&s"(q1), "=&s"(q2), "=&s"(q3)
        : "s"(sa));
    float c0 = crp[0], r0 = crp[1];
    accc = fmaf(c0, w0, accc);
#pragma unroll
    for (int jj = 0; jj < JB; ++jj) acc[jj] = fmaf(r0, fabsf(q0[jj] - w0), acc[jj]);
    float c1 = crp[2], r1 = crp[3];
    accc = fmaf(c1, w1, accc);
#pragma unroll
    for (int jj = 0; jj < JB; ++jj) acc[jj] = fmaf(r1, fabsf(q1[jj] - w1), acc[jj]);
    float c2 = crp[4], r2 = crp[5];
    accc = fmaf(c2, w2, accc);
#pragma unroll
    for (int jj = 0; jj < JB; ++jj) acc[jj] = fmaf(r2, fabsf(q2[jj] - w2), acc[jj]);
    float c3 = crp[6], r3 = crp[7];
    accc = fmaf(c3, w3, accc);
#pragma unroll
    for (int jj = 0; jj < JB; ++jj) acc[jj] = fmaf(r3, fabsf(q3[jj] - w3), acc[jj]);
    wup += 4 * NC; crp += 8;
    sa  += 4 * NC * sizeof(float);
  }

  // ---- cross-group reduction into partials ----
  if (g > 0) {
    float* pr = &s_red[g - 1][lane][0];
#pragma unroll
    for (int jj = 0; jj < JB; ++jj) pr[jj] = acc[jj];
    pr[JB] = accc;
  }
  __syncthreads();

  float* base = ws + (size_t)((b * NJT + jt) * 2 + s) * PBLK;
  if (g == 0) {
    float a[JB], aT = accc;
#pragma unroll
    for (int jj = 0; jj < JB; ++jj) a[jj] = acc[jj];
#pragma unroll
    for (int gg = 0; gg < 3; ++gg) {
      const float* pr = &s_red[gg][lane][0];
#pragma unroll
      for (int jj = 0; jj < JB; ++jj) a[jj] += pr[jj];
      aT += pr[JB];
    }
    float4 v0 = {a[0], a[1], a[2], a[3]};
    float4 v1 = {a[4], a[5], a[6], a[7]};
    *(float4*)(base + lane * PROW)     = v0;
    *(float4*)(base + lane * PROW + 4) = v1;
    base[lane * PROW + 8] = aT;
  }
  if (tid < JB) {
    base[128 * PROW + tid] = s_lin[0][tid] + s_lin[1][tid] + s_lin[2][tid] + s_lin[3][tid];
  }
  (void)s_max_un;
}

__global__ __launch_bounds__(NT) void adv_comb(
    const float* __restrict__ ws, const float* __restrict__ bu,
    const float* __restrict__ bl, const float* __restrict__ y,
    float* __restrict__ out)
{
  const int b = blockIdx.x;
  const int q = threadIdx.x >> 7;
  const int i = threadIdx.x & 127;
  __shared__ float s_max[8];

  float m = -INFINITY;
  float bui = 0.f, yi = 0.f;
  if (i < NC) { bui = bu[b * NC + i]; yi = y[b * NC + i]; }

  for (int jt = q; jt < NJT; jt += 4) {
    const int j0 = (jt < NJT - 1) ? jt * JB : (NC - JB);
    const float* p0 = ws + (size_t)((b * NJT + jt) * 2 + 0) * PBLK;
    const float* p1 = p0 + PBLK;
    if (i < NC) {
      float4 a0 = *(const float4*)(p0 + i * PROW);
      float4 a1 = *(const float4*)(p0 + i * PROW + 4);
      float  t0 = p0[i * PROW + 8];
      float4 c0 = *(const float4*)(p1 + i * PROW);
      float4 c1 = *(const float4*)(p1 + i * PROW + 4);
      float  t1 = p1[i * PROW + 8];
      float base_i = bui - BIGNEG * yi + t0 + t1;
      float a[JB] = {a0.x + c0.x, a0.y + c0.y, a0.z + c0.z, a0.w + c0.w,
                     a1.x + c1.x, a1.y + c1.y, a1.z + c1.z, a1.w + c1.w};
#pragma unroll
      for (int jj = 0; jj < JB; ++jj) {
        int j = j0 + jj;
        float R = p0[128 * PROW + jj] + p1[128 * PROW + jj];
        float v = a[jj] + base_i - bl[b * NC + j] - BIGNEG * (1.0f - y[b * NC + j]) - R;
        m = fmaxf(m, v);
      }
    }
  }

#pragma unroll
  for (int off = 32; off; off >>= 1) m = fmaxf(m, __shfl_down(m, off, 64));
  if ((threadIdx.x & 63) == 0) s_max[threadIdx.x >> 6] = m;
  __syncthreads();
  if (threadIdx.x == 0) {
    float r = s_max[0];
#pragma unroll
    for (int w = 1; w < 8; ++w) r = fmaxf(r, s_max[w]);
    out[b] = r;
  }
}

extern "C" void kernel_launch(void* const* d_in, const int* in_sizes, int n_in,
                              void* d_out, int out_size, void* d_ws, size_t ws_size,
                              hipStream_t stream) {
  // inputs: 0:x (unused), 1:z_tensor, 2:w_u, 3:b_u, 4:w_l, 5:b_l, 6:y_tensor
  const float* z  = (const float*)d_in[1];
  const float* wu = (const float*)d_in[2];
  const float* bu = (const float*)d_in[3];
  const float* wl = (const float*)d_in[4];
  const float* bl = (const float*)d_in[5];
  const float* y  = (const float*)d_in[6];
  float* ws = (float*)d_ws;

  adv_part<<<NJT * BATCH * 2, NT, 0, stream>>>(z, wu, wl, ws);
  adv_comb<<<BATCH, NT, 0, stream>>>(ws, bu, bl, y, (float*)d_out);
}